// Round 2
// baseline (15.380 us; speedup 1.0000x reference)
//
#include <hip/hip_runtime.h>
#include <math.h>

// Problem constants (match reference)
#define T_LEN   8192
#define D_DIM   128
#define NTHR    512               // 8 waves, single block (single CU)
#define OPT     16                // outputs per thread: 512*16 = 8192
#define NTAP    32                // rho in [-16, 15]; g(|rho|>=16) < 1e-9 -> negligible
#define GAUSS_C 0.39894228f

// Single fused kernel: conv (32 truncated taps) + noise + global min/max + normalize.
// One block => block-wide sync suffices for the global min/max; no workspace, no
// second launch, no counter init. Launch-overhead-bound by design.
__global__ __launch_bounds__(NTHR) void k_fused(
    const float* __restrict__ X, const float* __restrict__ weight,
    const float* __restrict__ noise, const float* __restrict__ sigma,
    float* __restrict__ out)
{
    __shared__ float wsc[D_DIM];    // softmax(w)_d * C / sigma_d
    __shared__ float inv2[D_DIM];   // 1/(2 sigma_d^2)
    __shared__ float g[NTAP];       // combined taps, g[k] = g(rho = k-16)
    __shared__ float red[4];
    __shared__ float rmin[8], rmax[8];

    const int tid = threadIdx.x;
    const int wv  = tid >> 6;       // wave id 0..7
    const int t0  = tid * OPT;

    // ---- spike window -> registers: i in [t0-16, t0+32), 48 floats ----
    // out t = t0+j needs i = t+15-k (k in [0,32)) -> m = j+31-k in [0,47]
    float W[48];
    const int base = t0 - 16;
    if (base >= 0 && base + 48 <= T_LEN) {       // all but threads 0 and 511
        #pragma unroll
        for (int q = 0; q < 12; ++q) {
            float4 x4 = *reinterpret_cast<const float4*>(&X[base + 4*q]);
            W[4*q+0] = x4.x > 0.5f ? 1.f : 0.f;
            W[4*q+1] = x4.y > 0.5f ? 1.f : 0.f;
            W[4*q+2] = x4.z > 0.5f ? 1.f : 0.f;
            W[4*q+3] = x4.w > 0.5f ? 1.f : 0.f;
        }
    } else {
        #pragma unroll
        for (int m = 0; m < 48; ++m) {
            int i = base + m;
            float x = (i >= 0 && i < T_LEN) ? X[i] : 0.f;
            W[m] = x > 0.5f ? 1.f : 0.f;
        }
    }
    // frozen noise -> registers
    float nzf[OPT];
    #pragma unroll
    for (int q = 0; q < 4; ++q) {
        float4 v = *reinterpret_cast<const float4*>(&noise[t0 + 4*q]);
        nzf[4*q+0] = v.x; nzf[4*q+1] = v.y; nzf[4*q+2] = v.z; nzf[4*q+3] = v.w;
    }

    // ---- softmax(weight) over D=128 (threads 0..127 = 2 waves) ----
    float w_e = 0.f;
    if (tid < 128) {
        float w = weight[tid];
        float m = w;
        #pragma unroll
        for (int off = 32; off >= 1; off >>= 1) m = fmaxf(m, __shfl_xor(m, off));
        if ((tid & 63) == 0) red[wv] = m;
    }
    __syncthreads();
    if (tid < 128) {
        float w = weight[tid];
        float m = fmaxf(red[0], red[1]);
        float e = __expf(w - m);
        float s = e;
        #pragma unroll
        for (int off = 32; off >= 1; off >>= 1) s += __shfl_xor(s, off);
        if ((tid & 63) == 0) red[2 + wv] = s;
        w_e = e;
    }
    __syncthreads();
    if (tid < 128) {
        float s  = red[2] + red[3];
        float sg = sigma[tid];
        wsc[tid]  = (w_e / s) * (GAUSS_C / sg);
        inv2[tid] = 1.f / (2.f * sg * sg);
    }
    __syncthreads();

    // ---- combined taps: 32 taps x 16 lanes x 8 sigma-channels each ----
    {
        int   k  = tid >> 4;              // tap 0..31
        int   d0 = (tid & 15) * 8;        // sigma-chunk
        float rho = (float)(k - 16);
        float r2  = rho * rho;
        float4 wa = *reinterpret_cast<const float4*>(&wsc[d0]);
        float4 wb = *reinterpret_cast<const float4*>(&wsc[d0 + 4]);
        float4 ia = *reinterpret_cast<const float4*>(&inv2[d0]);
        float4 ib = *reinterpret_cast<const float4*>(&inv2[d0 + 4]);
        float a = wa.x * __expf(-r2 * ia.x);
        a = fmaf(wa.y, __expf(-r2 * ia.y), a);
        a = fmaf(wa.z, __expf(-r2 * ia.z), a);
        a = fmaf(wa.w, __expf(-r2 * ia.w), a);
        a = fmaf(wb.x, __expf(-r2 * ib.x), a);
        a = fmaf(wb.y, __expf(-r2 * ib.y), a);
        a = fmaf(wb.z, __expf(-r2 * ib.z), a);
        a = fmaf(wb.w, __expf(-r2 * ib.w), a);
        #pragma unroll
        for (int off = 8; off >= 1; off >>= 1) a += __shfl_xor(a, off);
        if ((tid & 15) == 0) g[k] = a;
    }
    __syncthreads();

    // ---- taps -> registers (LDS broadcast reads) ----
    float gv[NTAP];
    #pragma unroll
    for (int q = 0; q < 8; ++q) {
        float4 g4 = *reinterpret_cast<const float4*>(&g[4*q]);
        gv[4*q+0] = g4.x; gv[4*q+1] = g4.y; gv[4*q+2] = g4.z; gv[4*q+3] = g4.w;
    }

    // ---- 32-tap conv, pure-register FMA: 16 outputs x 32 taps ----
    float acc[OPT];
    #pragma unroll
    for (int j = 0; j < OPT; ++j) {
        float a = 0.f;
        #pragma unroll
        for (int k = 0; k < NTAP; ++k)
            a = fmaf(W[j + 31 - k], gv[k], a);
        acc[j] = a + nzf[j];
    }

    // ---- block-wide (== global) min/max ----
    float mn = acc[0], mx = acc[0];
    #pragma unroll
    for (int j = 1; j < OPT; ++j) {
        mn = fminf(mn, acc[j]);
        mx = fmaxf(mx, acc[j]);
    }
    #pragma unroll
    for (int off = 32; off >= 1; off >>= 1) {
        mn = fminf(mn, __shfl_xor(mn, off));
        mx = fmaxf(mx, __shfl_xor(mx, off));
    }
    if ((tid & 63) == 0) { rmin[wv] = mn; rmax[wv] = mx; }
    __syncthreads();
    float gmn = rmin[0], gmx = rmax[0];
    #pragma unroll
    for (int i = 1; i < 8; ++i) {
        gmn = fminf(gmn, rmin[i]);
        gmx = fmaxf(gmx, rmax[i]);
    }
    const float inv = 1.f / (gmx - gmn);

    // ---- normalize + store ----
    #pragma unroll
    for (int q = 0; q < 4; ++q) {
        float4 o;
        o.x = (acc[4*q+0] - gmn) * inv;
        o.y = (acc[4*q+1] - gmn) * inv;
        o.z = (acc[4*q+2] - gmn) * inv;
        o.w = (acc[4*q+3] - gmn) * inv;
        *reinterpret_cast<float4*>(&out[t0 + 4*q]) = o;
    }
}

extern "C" void kernel_launch(void* const* d_in, const int* in_sizes, int n_in,
                              void* d_out, int out_size, void* d_ws, size_t ws_size,
                              hipStream_t stream) {
    const float* X      = (const float*)d_in[0];   // (1, 8192)
    const float* weight = (const float*)d_in[1];   // (1, 128)
    const float* noise  = (const float*)d_in[2];   // (1, 8192)
    const float* sigma  = (const float*)d_in[3];   // (128,)
    float* out = (float*)d_out;                    // (1, 8192) float32

    k_fused<<<1, NTHR, 0, stream>>>(X, weight, noise, sigma, out);
}